// Round 12
// baseline (241.331 us; speedup 1.0000x reference)
//
#include <hip/hip_runtime.h>
#include <cstddef>
#include <cstdint>

#define B 32
#define T 1024
#define J 128
#define H 1024

typedef unsigned short ushort_t;
typedef __attribute__((ext_vector_type(8))) short bf16x8;
typedef __attribute__((ext_vector_type(4))) float f32x4;

__device__ __forceinline__ unsigned short f2bf(float f) {
    union { float f; unsigned u; } v;
    v.f = f;
    return (unsigned short)((v.u + 0x7FFFu + ((v.u >> 16) & 1u)) >> 16);
}
__device__ __forceinline__ float bf2f(unsigned short s) {
    union { unsigned u; float f; } v;
    v.u = ((unsigned)s) << 16;
    return v.f;
}

// ---------------------------------------------------------------------------
// k_main: heterogeneous grid.
//  blocks 0..255   : gemm1 (128x128 tile, 512 thr, XCD-pinned 4 batches/XCD)
//  blocks 256..1279: uprep (64x64 u->uT transpose), XCD-ALIGNED with gemm1's
//                    batch pinning so u[b] is L2-resident for gemm1 staging.
// gemm1 LDS: Ss aliases As/Bs (dead after K loop) -> 38.4 KB -> 2 blocks/CU.
// ---------------------------------------------------------------------------
__global__ __launch_bounds__(512, 4) void k_main(const float* __restrict__ h,
                                                 const float* __restrict__ u,
                                                 const float* __restrict__ w,
                                                 const float* __restrict__ bscal,
                                                 ushort_t* __restrict__ Sb,
                                                 ushort_t* __restrict__ hbf,
                                                 ushort_t* __restrict__ uT,
                                                 float* __restrict__ Mrow,
                                                 float* __restrict__ pcm,
                                                 float* __restrict__ pcs) {
    __shared__ __align__(16) char smem[38912];
    const int tid = threadIdx.x;

    if (blockIdx.x >= 256) {
        // ---------------- uprep branch: 64x64 transpose tile ----------------
        // XCD-aligned: xcd = lid&7 handles batches 4*xcd .. 4*xcd+3 (= gemm1)
        ushort_t (*tile)[72] = (ushort_t (*)[72])smem;
        int xcd = blockIdx.x & 7;
        int seq2 = (blockIdx.x - 256) >> 3;    // 0..127 per XCD
        int b = xcd * 4 + (seq2 >> 5);
        int tile_i = seq2 & 31;
        int d0 = (tile_i & 15) * 64;
        int j0 = (tile_i >> 4) * 64;
        int jr = tid >> 3, c0 = (tid & 7) * 8;
        size_t src = ((size_t)(b << 7) + j0 + jr) * H + d0 + c0;
        float4 x = *(const float4*)&u[src];
        float4 y = *(const float4*)&u[src + 4];
        tile[jr][c0 + 0] = f2bf(x.x); tile[jr][c0 + 1] = f2bf(x.y);
        tile[jr][c0 + 2] = f2bf(x.z); tile[jr][c0 + 3] = f2bf(x.w);
        tile[jr][c0 + 4] = f2bf(y.x); tile[jr][c0 + 5] = f2bf(y.y);
        tile[jr][c0 + 6] = f2bf(y.z); tile[jr][c0 + 7] = f2bf(y.w);
        __syncthreads();
        int dr = tid >> 3, jc0 = (tid & 7) * 8;
        union { ushort_t us[8]; uint4 v; } t2;
#pragma unroll
        for (int i = 0; i < 8; ++i) t2.us[i] = tile[jc0 + i][dr];
        *(uint4*)&uT[((size_t)(b << 10) + d0 + dr) * J + j0 + jc0] = t2.v;
        return;
    }

    // ------------------------- gemm1 branch -------------------------------
    ushort_t* As = (ushort_t*)smem;                  // 16384 B
    ushort_t* Bs = (ushort_t*)(smem + 16384);        // 16384 B
    ushort_t* Ss = (ushort_t*)smem;                  // ALIAS: 64x136x2=17408 B
    float* rm_red = (float*)(smem + 32768);          // [2][128] = 1024 B
    float* cm_red = (float*)(smem + 33792);          // [4][128] = 2048 B
    float* cs_red = (float*)(smem + 35840);          // [4][128] = 2048 B
    float* suBs = (float*)(smem + 37888);            // [128]    = 512 B

    const int lid = blockIdx.x;
    const int b = (lid & 7) * 4 + (lid >> 6);
    const int tt = (lid >> 3) & 7;
    const int t0 = tt * 128;
    const float* wh = w;
    const float* wu = w + H;
    const float* wm = w + 2 * H;
    const int lane = tid & 63, wid = tid >> 6;
    const int wr = wid >> 1, wc = wid & 1;

    f32x4 acc[2][4] = {};
    float dotp[2] = {0.f, 0.f};

    const int srow = wid * 8 + (lane >> 3);   // 0..63
    const int su_ = lane & 7;
    const int r7 = lane >> 3;
    const int kk = (su_ ^ r7) << 3;

    for (int k0 = 0; k0 < H; k0 += 64) {
        float4 wh0 = *(const float4*)&wh[k0 + kk];
        float4 wh1 = *(const float4*)&wh[k0 + kk + 4];
        float4 wu0 = *(const float4*)&wu[k0 + kk];
        float4 wu1 = *(const float4*)&wu[k0 + kk + 4];
        float4 wm0 = *(const float4*)&wm[k0 + kk];
        float4 wm1 = *(const float4*)&wm[k0 + kk + 4];
        // ---- stage A: h f32 -> bf16, side-write hbf
#pragma unroll
        for (int w2 = 0; w2 < 2; ++w2) {
            int row = srow + w2 * 64;
            size_t hoff = ((size_t)(b << 10) + t0 + row) * H + k0 + kk;
            float4 x = *(const float4*)&h[hoff];
            float4 y = *(const float4*)&h[hoff + 4];
            union { ushort_t us[8]; uint4 v; } pk;
            pk.us[0] = f2bf(x.x); pk.us[1] = f2bf(x.y);
            pk.us[2] = f2bf(x.z); pk.us[3] = f2bf(x.w);
            pk.us[4] = f2bf(y.x); pk.us[5] = f2bf(y.y);
            pk.us[6] = f2bf(y.z); pk.us[7] = f2bf(y.w);
            *(uint4*)&As[row * 64 + (su_ << 3)] = pk.v;
            *(uint4*)&hbf[hoff] = pk.v;
        }
        // ---- stage B: u2 = wh + wm*u on the fly + fused wu dot
#pragma unroll
        for (int w2 = 0; w2 < 2; ++w2) {
            int row = srow + w2 * 64;
            size_t uoff = ((size_t)(b << 7) + row) * H + k0 + kk;
            float4 x = *(const float4*)&u[uoff];
            float4 y = *(const float4*)&u[uoff + 4];
            union { ushort_t us[8]; uint4 v; } pk;
            pk.us[0] = f2bf(wh0.x + wm0.x * x.x);
            pk.us[1] = f2bf(wh0.y + wm0.y * x.y);
            pk.us[2] = f2bf(wh0.z + wm0.z * x.z);
            pk.us[3] = f2bf(wh0.w + wm0.w * x.w);
            pk.us[4] = f2bf(wh1.x + wm1.x * y.x);
            pk.us[5] = f2bf(wh1.y + wm1.y * y.y);
            pk.us[6] = f2bf(wh1.z + wm1.z * y.z);
            pk.us[7] = f2bf(wh1.w + wm1.w * y.w);
            *(uint4*)&Bs[row * 64 + (su_ << 3)] = pk.v;
            dotp[w2] += wu0.x * x.x + wu0.y * x.y + wu0.z * x.z + wu0.w * x.w +
                        wu1.x * y.x + wu1.y * y.y + wu1.z * y.z + wu1.w * y.w;
        }
        __syncthreads();
#pragma unroll
        for (int ks = 0; ks < 2; ++ks) {
            bf16x8 af[2], bfr[4];
            int cbyte = ks * 64 + ((lane >> 4) << 4);
#pragma unroll
            for (int mi = 0; mi < 2; ++mi) {
                int row = wr * 32 + mi * 16 + (lane & 15);
                af[mi] = *(const bf16x8*)&As[row * 64 + ((cbyte ^ ((row & 7) << 4)) >> 1)];
            }
#pragma unroll
            for (int nj = 0; nj < 4; ++nj) {
                int row = wc * 64 + nj * 16 + (lane & 15);
                bfr[nj] = *(const bf16x8*)&Bs[row * 64 + ((cbyte ^ ((row & 7) << 4)) >> 1)];
            }
#pragma unroll
            for (int mi = 0; mi < 2; ++mi)
#pragma unroll
                for (int nj = 0; nj < 4; ++nj)
                    acc[mi][nj] = __builtin_amdgcn_mfma_f32_16x16x32_bf16(
                        af[mi], bfr[nj], acc[mi][nj], 0, 0, 0);
        }
        __syncthreads();
    }

    // ---- finalize suB: octet reduce (lanes su_=0..7 are consecutive)
    {
        float b0 = bscal[0];
#pragma unroll
        for (int w2 = 0; w2 < 2; ++w2) {
            float d = dotp[w2];
            d += __shfl_xor(d, 1);
            d += __shfl_xor(d, 2);
            d += __shfl_xor(d, 4);
            if (su_ == 0) suBs[srow + w2 * 64] = d + b0;
        }
    }
    __syncthreads();

    // ---- stats: row-max + column (max,sumexp) partials (no Ss writes yet)
    const int jbase = wc * 64 + (lane & 15);
    const int lq = lane >> 4;
    float rowmax[2][4];
#pragma unroll
    for (int mi = 0; mi < 2; ++mi)
#pragma unroll
        for (int r = 0; r < 4; ++r) rowmax[mi][r] = -INFINITY;
    float cmv[4], csv[4];
#pragma unroll
    for (int nj = 0; nj < 4; ++nj) {
        float su_v = suBs[jbase + nj * 16];
        float tmp[8];
        float cm = -INFINITY;
#pragma unroll
        for (int mi = 0; mi < 2; ++mi)
#pragma unroll
            for (int r = 0; r < 4; ++r) {
                float svb = bf2f(f2bf(acc[mi][nj][r] + su_v));
                tmp[mi * 4 + r] = svb;
                cm = fmaxf(cm, svb);
                rowmax[mi][r] = fmaxf(rowmax[mi][r], svb);
            }
        float cs = 0.0f;
#pragma unroll
        for (int i = 0; i < 8; ++i) cs += __expf(tmp[i] - cm);
        cmv[nj] = cm;
        csv[nj] = cs;
    }
#pragma unroll
    for (int mi = 0; mi < 2; ++mi)
#pragma unroll
        for (int r = 0; r < 4; ++r) {
            float v = rowmax[mi][r];
#pragma unroll
            for (int off = 1; off < 16; off <<= 1) v = fmaxf(v, __shfl_xor(v, off));
            if ((lane & 15) == 0) {
                int row = wr * 32 + mi * 16 + lq * 4 + r;
                rm_red[wc * 128 + row] = v;
            }
        }
#pragma unroll
    for (int nj = 0; nj < 4; ++nj) {
        float cm = cmv[nj], cs = csv[nj];
#pragma unroll
        for (int off = 16; off < 64; off <<= 1) {
            float om = __shfl_xor(cm, off);
            float os = __shfl_xor(cs, off);
            float nm = fmaxf(cm, om);
            cs = cs * __expf(cm - nm) + os * __expf(om - nm);
            cm = nm;
        }
        if (lane < 16) {
            cm_red[wr * 128 + wc * 64 + nj * 16 + lane] = cm;
            cs_red[wr * 128 + wc * 64 + nj * 16 + lane] = cs;
        }
    }
    __syncthreads();

    // ---- Mrow / pcm final reduction (reads rm/cm/cs; no barrier inside)
    if (tid < 128) {
        Mrow[(b << 10) + t0 + tid] = fmaxf(rm_red[tid], rm_red[128 + tid]);
    } else if (tid < 256) {
        int j = tid - 128;
        float m = cm_red[j], s = cs_red[j];
#pragma unroll
        for (int r = 1; r < 4; ++r) {
            float m2 = cm_red[r * 128 + j], s2 = cs_red[r * 128 + j];
            float nm = fmaxf(m, m2);
            s = s * __expf(m - nm) + s2 * __expf(m2 - nm);
            m = nm;
        }
        int col = (b << 7) + j;
        pcm[col * 8 + tt] = m;
        pcs[col * 8 + tt] = s;
    }

    // ---- two-phase Sb writeout via Ss alias of As/Bs (64 rows each)
#pragma unroll
    for (int ph = 0; ph < 2; ++ph) {
        if ((wr >> 1) == ph) {
#pragma unroll
            for (int nj = 0; nj < 4; ++nj) {
                float su_v = suBs[jbase + nj * 16];
#pragma unroll
                for (int mi = 0; mi < 2; ++mi)
#pragma unroll
                    for (int r = 0; r < 4; ++r) {
                        int rloc = (wr & 1) * 32 + mi * 16 + lq * 4 + r;
                        Ss[rloc * 136 + jbase + nj * 16] =
                            f2bf(acc[mi][nj][r] + su_v);
                    }
            }
        }
        __syncthreads();
#pragma unroll
        for (int pass = 0; pass < 2; ++pass) {
            int idx = pass * 512 + tid;   // 0..1023
            int r = idx >> 4;             // 0..63
            int c = (idx & 15) << 3;
            uint4 v = *(const uint4*)&Ss[r * 136 + c];
            *(uint4*)&Sb[((size_t)(b << 10) + t0 + ph * 64 + r) * J + c] = v;
        }
        __syncthreads();
    }
}

// ---------------------------------------------------------------------------
// k_q2c_part: self-contained bt softmax stats from Mrow, then partial
// q2c over a 64-row t-chunk reading hbf. grid (16, B), 256 thr.
// ---------------------------------------------------------------------------
__global__ __launch_bounds__(256) void k_q2c_part(const ushort_t* __restrict__ hbf,
                                                  const float* __restrict__ Mrow,
                                                  float* __restrict__ part) {
    int tc = blockIdx.x, b = blockIdx.y;
    int tid = threadIdx.x;
    __shared__ float red[256];
    __shared__ float wbt[64];
    const float* mr = Mrow + (b << 10);
    float m = fmaxf(fmaxf(mr[tid], mr[tid + 256]), fmaxf(mr[tid + 512], mr[tid + 768]));
    red[tid] = m;
    __syncthreads();
    for (int o = 128; o; o >>= 1) {
        if (tid < o) red[tid] = fmaxf(red[tid], red[tid + o]);
        __syncthreads();
    }
    m = red[0];
    __syncthreads();
    float s = 0.0f;
    for (int t = tid; t < T; t += 256) s += __expf(mr[t] - m);
    red[tid] = s;
    __syncthreads();
    for (int o = 128; o; o >>= 1) {
        if (tid < o) red[tid] += red[tid + o];
        __syncthreads();
    }
    float binv = 1.0f / red[0];
    if (tid < 64) wbt[tid] = __expf(mr[tc * 64 + tid] - m) * binv;
    __syncthreads();

    int dd = tid * 4;
    float acc0 = 0.f, acc1 = 0.f, acc2 = 0.f, acc3 = 0.f;
#pragma unroll 4
    for (int i = 0; i < 64; ++i) {
        int t = tc * 64 + i;
        uint2 v = *(const uint2*)&hbf[((size_t)(b << 10) + t) * H + dd];
        const ushort_t* us = (const ushort_t*)&v;
        float wv = wbt[i];
        acc0 += wv * bf2f(us[0]);
        acc1 += wv * bf2f(us[1]);
        acc2 += wv * bf2f(us[2]);
        acc3 += wv * bf2f(us[3]);
    }
    size_t pb = (((size_t)b * 16 + tc) << 10) + dd;
    *(float4*)&part[pb] = make_float4(acc0, acc1, acc2, acc3);
}

// ---------------------------------------------------------------------------
// k_gemm2g: prologue reduces (pcm,pcs)->cmax/cinv and qpart->q2c into LDS;
// stages P with fused softmax normalize; c2q = P @ u via MFMA (A=uT rows=d,
// B=P cols=t). Epilogue: c2q tile staged in LDS aliasing Ps/Us -> 35 KB.
// G written row-contiguous (full 128B lines).
// ---------------------------------------------------------------------------
__global__ __launch_bounds__(256) void k_gemm2g(const ushort_t* __restrict__ Sb,
                                                const ushort_t* __restrict__ uT,
                                                const ushort_t* __restrict__ hbf,
                                                const float* __restrict__ pcm,
                                                const float* __restrict__ pcs,
                                                const float* __restrict__ qpart,
                                                float* __restrict__ G) {
    __shared__ __align__(16) char smem[33792];   // Ps(16K)+Us(16K) | cst(64x132 f32)
    __shared__ float cmaxs[128], cinvs[128], q2cs[128];
    ushort_t* Ps = (ushort_t*)smem;
    ushort_t* Us = (ushort_t*)(smem + 16384);
    float* cst = (float*)smem;

    const int lid = blockIdx.x;
    const int seq = lid >> 3;
    const int b = (lid & 7) * 4 + (seq >> 6);
    const int inner = seq & 63;
    const int d0 = (inner >> 3) * 128;
    const int t0 = (inner & 7) * 128;
    const int tid = threadIdx.x;
    const int lane = tid & 63, wid = tid >> 6;
    const int wd = wid >> 1, wt = wid & 1;

    if (tid < 128) {
        int col = (b << 7) + tid;
        float m = -INFINITY, s = 0.0f;
#pragma unroll
        for (int r = 0; r < 8; ++r) {
            float m2 = pcm[col * 8 + r], s2 = pcs[col * 8 + r];
            float nm = fmaxf(m, m2);
            s = s * __expf(m - nm) + s2 * __expf(m2 - nm);
            m = nm;
        }
        cmaxs[tid] = m;
        cinvs[tid] = 1.0f / s;
    } else {
        int d = d0 + tid - 128;
        float a = 0.0f;
#pragma unroll
        for (int tc = 0; tc < 16; ++tc)
            a += qpart[(((size_t)b * 16 + tc) << 10) + d];
        q2cs[tid - 128] = a;
    }
    __syncthreads();

    f32x4 acc[4][4] = {};
    for (int j0 = 0; j0 < J; j0 += 64) {
#pragma unroll
        for (int w = 0; w < 4; ++w) {
            int row = w * 32 + (tid >> 3);
            int u_ = tid & 7;
            int cb = (u_ ^ ((tid >> 3) & 7)) << 4;
            uint4 va = *(const uint4*)((const char*)Sb +
                       (((size_t)(b << 10) + t0 + row) * J + j0) * 2 + cb);
            int jb = j0 + (cb >> 1);
            union { ushort_t us[8]; uint4 v; } pp;
            pp.v = va;
#pragma unroll
            for (int i = 0; i < 8; ++i)
                pp.us[i] = f2bf(__expf(bf2f(pp.us[i]) - cmaxs[jb + i]) * cinvs[jb + i]);
            *(uint4*)&Ps[row * 64 + (u_ << 3)] = pp.v;
            uint4 vb = *(const uint4*)((const char*)uT +
                       (((size_t)(b << 10) + d0 + row) * J + j0) * 2 + cb);
            *(uint4*)&Us[row * 64 + (u_ << 3)] = vb;
        }
        __syncthreads();
#pragma unroll
        for (int ks = 0; ks < 2; ++ks) {
            bf16x8 af[4], bfr[4];
            int cbyte = ks * 64 + ((lane >> 4) << 4);
#pragma unroll
            for (int mi = 0; mi < 4; ++mi) {
                int row = wd * 64 + mi * 16 + (lane & 15);
                af[mi] = *(const bf16x8*)&Us[row * 64 + ((cbyte ^ ((row & 7) << 4)) >> 1)];
            }
#pragma unroll
            for (int nj = 0; nj < 4; ++nj) {
                int row = wt * 64 + nj * 16 + (lane & 15);
                bfr[nj] = *(const bf16x8*)&Ps[row * 64 + ((cbyte ^ ((row & 7) << 4)) >> 1)];
            }
#pragma unroll
            for (int mi = 0; mi < 4; ++mi)
#pragma unroll
                for (int nj = 0; nj < 4; ++nj)
                    acc[mi][nj] = __builtin_amdgcn_mfma_f32_16x16x32_bf16(
                        af[mi], bfr[nj], acc[mi][nj], 0, 0, 0);
        }
        __syncthreads();
    }

    const int lane15 = lane & 15, lq = lane >> 4;
#pragma unroll
    for (int th = 0; th < 2; ++th) {
        if (wt == th) {
#pragma unroll
            for (int mi = 0; mi < 4; ++mi)
#pragma unroll
                for (int nj = 0; nj < 4; ++nj) {
                    int r = nj * 16 + lane15;
                    int c = wd * 64 + mi * 16 + lq * 4;
                    f32x4 a = acc[mi][nj];
                    *(float4*)&cst[r * 132 + c] =
                        make_float4(a[0], a[1], a[2], a[3]);
                }
        }
        __syncthreads();
#pragma unroll
        for (int it = 0; it < 8; ++it) {
            int idx = it * 256 + tid;
            int r = idx >> 5;
            int c4 = (idx & 31) * 4;
            int trow = t0 + th * 64 + r;
            int drow = d0 + c4;
            float4 cv = *(const float4*)&cst[r * 132 + c4];
            size_t rowoff = (size_t)(b << 10) + trow;
            uint2 h2 = *(const uint2*)&hbf[rowoff * H + drow];
            const ushort_t* hu = (const ushort_t*)&h2;
            float4 hv = make_float4(bf2f(hu[0]), bf2f(hu[1]), bf2f(hu[2]), bf2f(hu[3]));
            float4 qv = *(const float4*)&q2cs[c4];
            size_t gp = rowoff * (4 * H) + drow;
            *(float4*)&G[gp] = hv;
            *(float4*)&G[gp + H] = cv;
            *(float4*)&G[gp + 2 * H] = make_float4(hv.x * cv.x, hv.y * cv.y,
                                                   hv.z * cv.z, hv.w * cv.w);
            *(float4*)&G[gp + 3 * H] = make_float4(hv.x * qv.x, hv.y * qv.y,
                                                   hv.z * qv.z, hv.w * qv.w);
        }
        __syncthreads();
    }
}

extern "C" void kernel_launch(void* const* d_in, const int* in_sizes, int n_in,
                              void* d_out, int out_size, void* d_ws, size_t ws_size,
                              hipStream_t stream) {
    const float* h = (const float*)d_in[0];
    const float* u = (const float*)d_in[1];
    const float* w = (const float*)d_in[2];
    const float* bb = (const float*)d_in[3];
    float* G = (float*)d_out;

    char* p = (char*)d_ws;
    ushort_t* Sb = (ushort_t*)p; p += (size_t)B * T * J * 2;
    ushort_t* uT = (ushort_t*)p; p += (size_t)B * H * J * 2;
    ushort_t* hbf = (ushort_t*)p; p += (size_t)B * T * H * 2;
    float* pcm = (float*)p; p += (size_t)B * J * 8 * 4;
    float* pcs = (float*)p; p += (size_t)B * J * 8 * 4;
    float* Mrow = (float*)p; p += B * T * 4;
    float* qpart = (float*)p;  // B*16*H*4

    k_main<<<dim3(1280), 512, 0, stream>>>(h, u, w, bb, Sb, hbf, uT, Mrow, pcm, pcs);
    k_q2c_part<<<dim3(16, B), 256, 0, stream>>>(hbf, Mrow, qpart);
    k_gemm2g<<<dim3(2048), 256, 0, stream>>>(Sb, uT, hbf, pcm, pcs, qpart, G);
}

// Round 13
// 162.320 us; speedup vs baseline: 1.4868x; 1.4868x over previous
//
#include <hip/hip_runtime.h>
#include <cstddef>
#include <cstdint>

#define B 32
#define T 1024
#define J 128
#define H 1024

typedef unsigned short ushort_t;
typedef __attribute__((ext_vector_type(8))) short bf16x8;
typedef __attribute__((ext_vector_type(4))) float f32x4;
typedef __attribute__((ext_vector_type(4))) float fvec4;

__device__ __forceinline__ unsigned short f2bf(float f) {
    union { float f; unsigned u; } v;
    v.f = f;
    return (unsigned short)((v.u + 0x7FFFu + ((v.u >> 16) & 1u)) >> 16);
}
__device__ __forceinline__ float bf2f(unsigned short s) {
    union { unsigned u; float f; } v;
    v.u = ((unsigned)s) << 16;
    return v.f;
}
// nontemporal full-line store (ext-vector type; HIP_vector_type rejected)
__device__ __forceinline__ void nt_st4(float* p, float4 v) {
    fvec4 t = {v.x, v.y, v.z, v.w};
    __builtin_nontemporal_store(t, (fvec4*)p);
}

// ---------------------------------------------------------------------------
// k_main: heterogeneous grid.
//  blocks 0..255   : gemm1 (128x128 tile, 512 thr, XCD-pinned 4 batches/XCD)
//  blocks 256..1279: uprep (one 64x64 u->uT bf16 transpose tile each)
// ---------------------------------------------------------------------------
__global__ __launch_bounds__(512) void k_main(const float* __restrict__ h,
                                              const float* __restrict__ u,
                                              const float* __restrict__ w,
                                              const float* __restrict__ bscal,
                                              ushort_t* __restrict__ Sb,
                                              ushort_t* __restrict__ hbf,
                                              ushort_t* __restrict__ uT,
                                              float* __restrict__ Mrow,
                                              float* __restrict__ pcm,
                                              float* __restrict__ pcs) {
    __shared__ __align__(16) char smem[73216];
    const int tid = threadIdx.x;

    if (blockIdx.x >= 256) {
        // ---------------- uprep branch: 64x64 transpose tile ----------------
        ushort_t (*tile)[72] = (ushort_t (*)[72])smem;
        int idx = blockIdx.x - 256;            // 0..1023
        int d0 = (idx & 15) * 64;
        int j0 = ((idx >> 4) & 1) * 64;
        int b = idx >> 5;
        int jr = tid >> 3, c0 = (tid & 7) * 8;
        size_t src = ((size_t)(b << 7) + j0 + jr) * H + d0 + c0;
        float4 x = *(const float4*)&u[src];
        float4 y = *(const float4*)&u[src + 4];
        tile[jr][c0 + 0] = f2bf(x.x); tile[jr][c0 + 1] = f2bf(x.y);
        tile[jr][c0 + 2] = f2bf(x.z); tile[jr][c0 + 3] = f2bf(x.w);
        tile[jr][c0 + 4] = f2bf(y.x); tile[jr][c0 + 5] = f2bf(y.y);
        tile[jr][c0 + 6] = f2bf(y.z); tile[jr][c0 + 7] = f2bf(y.w);
        __syncthreads();
        int dr = tid >> 3, jc0 = (tid & 7) * 8;
        union { ushort_t us[8]; uint4 v; } t2;
#pragma unroll
        for (int i = 0; i < 8; ++i) t2.us[i] = tile[jc0 + i][dr];
        *(uint4*)&uT[((size_t)(b << 10) + d0 + dr) * J + j0 + jc0] = t2.v;
        return;
    }

    // ------------------------- gemm1 branch -------------------------------
    ushort_t* As = (ushort_t*)smem;                  // 16384 B
    ushort_t* Bs = (ushort_t*)(smem + 16384);        // 16384 B
    ushort_t* Ss = (ushort_t*)(smem + 32768);        // 34816 B (128 x 136)
    float* rm_red = (float*)(smem + 67584);          // [2][128]
    float* cm_red = (float*)(smem + 68608);          // [4][128]
    float* cs_red = (float*)(smem + 70656);          // [4][128]
    float* suBs = (float*)(smem + 72704);            // [128]

    const int lid = blockIdx.x;
    const int b = (lid & 7) * 4 + (lid >> 6);
    const int tt = (lid >> 3) & 7;
    const int t0 = tt * 128;
    const float* wh = w;
    const float* wu = w + H;
    const float* wm = w + 2 * H;
    const int lane = tid & 63, wid = tid >> 6;
    const int wr = wid >> 1, wc = wid & 1;

    f32x4 acc[2][4] = {};
    float dotp[2] = {0.f, 0.f};

    const int srow = wid * 8 + (lane >> 3);   // 0..63
    const int su_ = lane & 7;
    const int r7 = lane >> 3;
    const int kk = (su_ ^ r7) << 3;

    for (int k0 = 0; k0 < H; k0 += 64) {
        float4 wh0 = *(const float4*)&wh[k0 + kk];
        float4 wh1 = *(const float4*)&wh[k0 + kk + 4];
        float4 wu0 = *(const float4*)&wu[k0 + kk];
        float4 wu1 = *(const float4*)&wu[k0 + kk + 4];
        float4 wm0 = *(const float4*)&wm[k0 + kk];
        float4 wm1 = *(const float4*)&wm[k0 + kk + 4];
        // ---- stage A: h f32 -> bf16, side-write hbf
#pragma unroll
        for (int w2 = 0; w2 < 2; ++w2) {
            int row = srow + w2 * 64;
            size_t hoff = ((size_t)(b << 10) + t0 + row) * H + k0 + kk;
            float4 x = *(const float4*)&h[hoff];
            float4 y = *(const float4*)&h[hoff + 4];
            union { ushort_t us[8]; uint4 v; } pk;
            pk.us[0] = f2bf(x.x); pk.us[1] = f2bf(x.y);
            pk.us[2] = f2bf(x.z); pk.us[3] = f2bf(x.w);
            pk.us[4] = f2bf(y.x); pk.us[5] = f2bf(y.y);
            pk.us[6] = f2bf(y.z); pk.us[7] = f2bf(y.w);
            *(uint4*)&As[row * 64 + (su_ << 3)] = pk.v;
            *(uint4*)&hbf[hoff] = pk.v;
        }
        // ---- stage B: u2 = wh + wm*u on the fly + fused wu dot
#pragma unroll
        for (int w2 = 0; w2 < 2; ++w2) {
            int row = srow + w2 * 64;
            size_t uoff = ((size_t)(b << 7) + row) * H + k0 + kk;
            float4 x = *(const float4*)&u[uoff];
            float4 y = *(const float4*)&u[uoff + 4];
            union { ushort_t us[8]; uint4 v; } pk;
            pk.us[0] = f2bf(wh0.x + wm0.x * x.x);
            pk.us[1] = f2bf(wh0.y + wm0.y * x.y);
            pk.us[2] = f2bf(wh0.z + wm0.z * x.z);
            pk.us[3] = f2bf(wh0.w + wm0.w * x.w);
            pk.us[4] = f2bf(wh1.x + wm1.x * y.x);
            pk.us[5] = f2bf(wh1.y + wm1.y * y.y);
            pk.us[6] = f2bf(wh1.z + wm1.z * y.z);
            pk.us[7] = f2bf(wh1.w + wm1.w * y.w);
            *(uint4*)&Bs[row * 64 + (su_ << 3)] = pk.v;
            dotp[w2] += wu0.x * x.x + wu0.y * x.y + wu0.z * x.z + wu0.w * x.w +
                        wu1.x * y.x + wu1.y * y.y + wu1.z * y.z + wu1.w * y.w;
        }
        __syncthreads();
#pragma unroll
        for (int ks = 0; ks < 2; ++ks) {
            bf16x8 af[2], bfr[4];
            int cbyte = ks * 64 + ((lane >> 4) << 4);
#pragma unroll
            for (int mi = 0; mi < 2; ++mi) {
                int row = wr * 32 + mi * 16 + (lane & 15);
                af[mi] = *(const bf16x8*)&As[row * 64 + ((cbyte ^ ((row & 7) << 4)) >> 1)];
            }
#pragma unroll
            for (int nj = 0; nj < 4; ++nj) {
                int row = wc * 64 + nj * 16 + (lane & 15);
                bfr[nj] = *(const bf16x8*)&Bs[row * 64 + ((cbyte ^ ((row & 7) << 4)) >> 1)];
            }
#pragma unroll
            for (int mi = 0; mi < 2; ++mi)
#pragma unroll
                for (int nj = 0; nj < 4; ++nj)
                    acc[mi][nj] = __builtin_amdgcn_mfma_f32_16x16x32_bf16(
                        af[mi], bfr[nj], acc[mi][nj], 0, 0, 0);
        }
        __syncthreads();
    }

    // ---- finalize suB: octet reduce (lanes su_=0..7 are consecutive)
    {
        float b0 = bscal[0];
#pragma unroll
        for (int w2 = 0; w2 < 2; ++w2) {
            float d = dotp[w2];
            d += __shfl_xor(d, 1);
            d += __shfl_xor(d, 2);
            d += __shfl_xor(d, 4);
            if (su_ == 0) suBs[srow + w2 * 64] = d + b0;
        }
    }
    __syncthreads();

    // ---- epilogue: +suB, S -> LDS, row-max + column partials
    const int jbase = wc * 64 + (lane & 15);
    const int lq = lane >> 4;
    float rowmax[2][4];
#pragma unroll
    for (int mi = 0; mi < 2; ++mi)
#pragma unroll
        for (int r = 0; r < 4; ++r) rowmax[mi][r] = -INFINITY;
    float cmv[4], csv[4];
#pragma unroll
    for (int nj = 0; nj < 4; ++nj) {
        float su_v = suBs[jbase + nj * 16];
        float tmp[8];
        float cm = -INFINITY;
#pragma unroll
        for (int mi = 0; mi < 2; ++mi)
#pragma unroll
            for (int r = 0; r < 4; ++r) {
                float sv = acc[mi][nj][r] + su_v;
                unsigned short sb = f2bf(sv);
                float svb = bf2f(sb);
                int tloc = wr * 32 + mi * 16 + lq * 4 + r;
                Ss[tloc * 136 + jbase + nj * 16] = sb;
                tmp[mi * 4 + r] = svb;
                cm = fmaxf(cm, svb);
                rowmax[mi][r] = fmaxf(rowmax[mi][r], svb);
            }
        float cs = 0.0f;
#pragma unroll
        for (int i = 0; i < 8; ++i) cs += __expf(tmp[i] - cm);
        cmv[nj] = cm;
        csv[nj] = cs;
    }
#pragma unroll
    for (int mi = 0; mi < 2; ++mi)
#pragma unroll
        for (int r = 0; r < 4; ++r) {
            float v = rowmax[mi][r];
#pragma unroll
            for (int off = 1; off < 16; off <<= 1) v = fmaxf(v, __shfl_xor(v, off));
            if ((lane & 15) == 0) {
                int row = wr * 32 + mi * 16 + lq * 4 + r;
                rm_red[wc * 128 + row] = v;
            }
        }
#pragma unroll
    for (int nj = 0; nj < 4; ++nj) {
        float cm = cmv[nj], cs = csv[nj];
#pragma unroll
        for (int off = 16; off < 64; off <<= 1) {
            float om = __shfl_xor(cm, off);
            float os = __shfl_xor(cs, off);
            float nm = fmaxf(cm, om);
            cs = cs * __expf(cm - nm) + os * __expf(om - nm);
            cm = nm;
        }
        if (lane < 16) {
            cm_red[wr * 128 + wc * 64 + nj * 16 + lane] = cm;
            cs_red[wr * 128 + wc * 64 + nj * 16 + lane] = cs;
        }
    }
    __syncthreads();
    // coalesced Sb writeout: 128 rows x 256 B
#pragma unroll
    for (int pass = 0; pass < 4; ++pass) {
        int idx = pass * 512 + tid;
        int r = idx >> 4;
        int c = (idx & 15) << 3;
        uint4 v = *(const uint4*)&Ss[r * 136 + c];
        *(uint4*)&Sb[((size_t)(b << 10) + t0 + r) * J + c] = v;
    }
    if (tid < 128) {
        Mrow[(b << 10) + t0 + tid] = fmaxf(rm_red[tid], rm_red[128 + tid]);
    } else if (tid < 256) {
        int j = tid - 128;
        float m = cm_red[j], s = cs_red[j];
#pragma unroll
        for (int r = 1; r < 4; ++r) {
            float m2 = cm_red[r * 128 + j], s2 = cs_red[r * 128 + j];
            float nm = fmaxf(m, m2);
            s = s * __expf(m - nm) + s2 * __expf(m2 - nm);
            m = nm;
        }
        int col = (b << 7) + j;
        pcm[col * 8 + tt] = m;
        pcs[col * 8 + tt] = s;
    }
}

// ---------------------------------------------------------------------------
// k_q2c_part: self-contained bt softmax stats from Mrow, then partial
// q2c over a 64-row t-chunk reading hbf. grid (16, B), 256 thr.
// ---------------------------------------------------------------------------
__global__ __launch_bounds__(256) void k_q2c_part(const ushort_t* __restrict__ hbf,
                                                  const float* __restrict__ Mrow,
                                                  float* __restrict__ part) {
    int tc = blockIdx.x, b = blockIdx.y;
    int tid = threadIdx.x;
    __shared__ float red[256];
    __shared__ float wbt[64];
    const float* mr = Mrow + (b << 10);
    float m = fmaxf(fmaxf(mr[tid], mr[tid + 256]), fmaxf(mr[tid + 512], mr[tid + 768]));
    red[tid] = m;
    __syncthreads();
    for (int o = 128; o; o >>= 1) {
        if (tid < o) red[tid] = fmaxf(red[tid], red[tid + o]);
        __syncthreads();
    }
    m = red[0];
    __syncthreads();
    float s = 0.0f;
    for (int t = tid; t < T; t += 256) s += __expf(mr[t] - m);
    red[tid] = s;
    __syncthreads();
    for (int o = 128; o; o >>= 1) {
        if (tid < o) red[tid] += red[tid + o];
        __syncthreads();
    }
    float binv = 1.0f / red[0];
    if (tid < 64) wbt[tid] = __expf(mr[tc * 64 + tid] - m) * binv;
    __syncthreads();

    int dd = tid * 4;
    float acc0 = 0.f, acc1 = 0.f, acc2 = 0.f, acc3 = 0.f;
#pragma unroll 4
    for (int i = 0; i < 64; ++i) {
        int t = tc * 64 + i;
        uint2 v = *(const uint2*)&hbf[((size_t)(b << 10) + t) * H + dd];
        const ushort_t* us = (const ushort_t*)&v;
        float wv = wbt[i];
        acc0 += wv * bf2f(us[0]);
        acc1 += wv * bf2f(us[1]);
        acc2 += wv * bf2f(us[2]);
        acc3 += wv * bf2f(us[3]);
    }
    size_t pb = (((size_t)b * 16 + tc) << 10) + dd;
    *(float4*)&part[pb] = make_float4(acc0, acc1, acc2, acc3);
}

// ---------------------------------------------------------------------------
// k_gemm2g: prologue reduces (pcm,pcs)->cmax/cinv and qpart->q2c into LDS;
// stages P with fused softmax normalize; c2q = P @ u via MFMA (A=uT rows=d,
// B=P cols=t). Epilogue: c2q staged in LDS aliasing Ps/Us (35 KB);
// G written row-contiguous with NONTEMPORAL full-128B-line stores
// (keeps Sb/uT L2-resident; no partial-line penalty since R7's coalescing).
// ---------------------------------------------------------------------------
__global__ __launch_bounds__(256) void k_gemm2g(const ushort_t* __restrict__ Sb,
                                                const ushort_t* __restrict__ uT,
                                                const ushort_t* __restrict__ hbf,
                                                const float* __restrict__ pcm,
                                                const float* __restrict__ pcs,
                                                const float* __restrict__ qpart,
                                                float* __restrict__ G) {
    __shared__ __align__(16) char smem[33792];   // Ps(16K)+Us(16K) | cst(64x132 f32)
    __shared__ float cmaxs[128], cinvs[128], q2cs[128];
    ushort_t* Ps = (ushort_t*)smem;
    ushort_t* Us = (ushort_t*)(smem + 16384);
    float* cst = (float*)smem;

    const int lid = blockIdx.x;
    const int seq = lid >> 3;
    const int b = (lid & 7) * 4 + (seq >> 6);
    const int inner = seq & 63;
    const int d0 = (inner >> 3) * 128;
    const int t0 = (inner & 7) * 128;
    const int tid = threadIdx.x;
    const int lane = tid & 63, wid = tid >> 6;
    const int wd = wid >> 1, wt = wid & 1;

    if (tid < 128) {
        int col = (b << 7) + tid;
        float m = -INFINITY, s = 0.0f;
#pragma unroll
        for (int r = 0; r < 8; ++r) {
            float m2 = pcm[col * 8 + r], s2 = pcs[col * 8 + r];
            float nm = fmaxf(m, m2);
            s = s * __expf(m - nm) + s2 * __expf(m2 - nm);
            m = nm;
        }
        cmaxs[tid] = m;
        cinvs[tid] = 1.0f / s;
    } else {
        int d = d0 + tid - 128;
        float a = 0.0f;
#pragma unroll
        for (int tc = 0; tc < 16; ++tc)
            a += qpart[(((size_t)b * 16 + tc) << 10) + d];
        q2cs[tid - 128] = a;
    }
    __syncthreads();

    f32x4 acc[4][4] = {};
    for (int j0 = 0; j0 < J; j0 += 64) {
#pragma unroll
        for (int w = 0; w < 4; ++w) {
            int row = w * 32 + (tid >> 3);
            int u_ = tid & 7;
            int cb = (u_ ^ ((tid >> 3) & 7)) << 4;
            uint4 va = *(const uint4*)((const char*)Sb +
                       (((size_t)(b << 10) + t0 + row) * J + j0) * 2 + cb);
            int jb = j0 + (cb >> 1);
            union { ushort_t us[8]; uint4 v; } pp;
            pp.v = va;
#pragma unroll
            for (int i = 0; i < 8; ++i)
                pp.us[i] = f2bf(__expf(bf2f(pp.us[i]) - cmaxs[jb + i]) * cinvs[jb + i]);
            *(uint4*)&Ps[row * 64 + (u_ << 3)] = pp.v;
            uint4 vb = *(const uint4*)((const char*)uT +
                       (((size_t)(b << 10) + d0 + row) * J + j0) * 2 + cb);
            *(uint4*)&Us[row * 64 + (u_ << 3)] = vb;
        }
        __syncthreads();
#pragma unroll
        for (int ks = 0; ks < 2; ++ks) {
            bf16x8 af[4], bfr[4];
            int cbyte = ks * 64 + ((lane >> 4) << 4);
#pragma unroll
            for (int mi = 0; mi < 4; ++mi) {
                int row = wd * 64 + mi * 16 + (lane & 15);
                af[mi] = *(const bf16x8*)&Us[row * 64 + ((cbyte ^ ((row & 7) << 4)) >> 1)];
            }
#pragma unroll
            for (int nj = 0; nj < 4; ++nj) {
                int row = wt * 64 + nj * 16 + (lane & 15);
                bfr[nj] = *(const bf16x8*)&Ps[row * 64 + ((cbyte ^ ((row & 7) << 4)) >> 1)];
            }
#pragma unroll
            for (int mi = 0; mi < 4; ++mi)
#pragma unroll
                for (int nj = 0; nj < 4; ++nj)
                    acc[mi][nj] = __builtin_amdgcn_mfma_f32_16x16x32_bf16(
                        af[mi], bfr[nj], acc[mi][nj], 0, 0, 0);
        }
        __syncthreads();
    }

    const int lane15 = lane & 15, lq = lane >> 4;
#pragma unroll
    for (int th = 0; th < 2; ++th) {
        if (wt == th) {
#pragma unroll
            for (int mi = 0; mi < 4; ++mi)
#pragma unroll
                for (int nj = 0; nj < 4; ++nj) {
                    int r = nj * 16 + lane15;
                    int c = wd * 64 + mi * 16 + lq * 4;
                    f32x4 a = acc[mi][nj];
                    *(float4*)&cst[r * 132 + c] =
                        make_float4(a[0], a[1], a[2], a[3]);
                }
        }
        __syncthreads();
#pragma unroll
        for (int it = 0; it < 8; ++it) {
            int idx = it * 256 + tid;
            int r = idx >> 5;
            int c4 = (idx & 31) * 4;
            int trow = t0 + th * 64 + r;
            int drow = d0 + c4;
            float4 cv = *(const float4*)&cst[r * 132 + c4];
            size_t rowoff = (size_t)(b << 10) + trow;
            uint2 h2 = *(const uint2*)&hbf[rowoff * H + drow];
            const ushort_t* hu = (const ushort_t*)&h2;
            float4 hv = make_float4(bf2f(hu[0]), bf2f(hu[1]), bf2f(hu[2]), bf2f(hu[3]));
            float4 qv = *(const float4*)&q2cs[c4];
            size_t gp = rowoff * (4 * H) + drow;
            nt_st4(&G[gp], hv);
            nt_st4(&G[gp + H], cv);
            nt_st4(&G[gp + 2 * H], make_float4(hv.x * cv.x, hv.y * cv.y,
                                               hv.z * cv.z, hv.w * cv.w));
            nt_st4(&G[gp + 3 * H], make_float4(hv.x * qv.x, hv.y * qv.y,
                                               hv.z * qv.z, hv.w * qv.w));
        }
        __syncthreads();
    }
}

extern "C" void kernel_launch(void* const* d_in, const int* in_sizes, int n_in,
                              void* d_out, int out_size, void* d_ws, size_t ws_size,
                              hipStream_t stream) {
    const float* h = (const float*)d_in[0];
    const float* u = (const float*)d_in[1];
    const float* w = (const float*)d_in[2];
    const float* bb = (const float*)d_in[3];
    float* G = (float*)d_out;

    char* p = (char*)d_ws;
    ushort_t* Sb = (ushort_t*)p; p += (size_t)B * T * J * 2;
    ushort_t* uT = (ushort_t*)p; p += (size_t)B * H * J * 2;
    ushort_t* hbf = (ushort_t*)p; p += (size_t)B * T * H * 2;
    float* pcm = (float*)p; p += (size_t)B * J * 8 * 4;
    float* pcs = (float*)p; p += (size_t)B * J * 8 * 4;
    float* Mrow = (float*)p; p += B * T * 4;
    float* qpart = (float*)p;  // B*16*H*4

    k_main<<<dim3(1280), 512, 0, stream>>>(h, u, w, bb, Sb, hbf, uT, Mrow, pcm, pcs);
    k_q2c_part<<<dim3(16, B), 256, 0, stream>>>(hbf, Mrow, qpart);
    k_gemm2g<<<dim3(2048), 256, 0, stream>>>(Sb, uT, hbf, pcm, pcs, qpart, G);
}